// Round 6
// baseline (481.687 us; speedup 1.0000x reference)
//
#include <hip/hip_runtime.h>
#include <math.h>

#define BATCH 4
#define CIN   512
#define PABN  64
#define HW    4096
#define PROW  4356            // 66*66 padded pixel rows

typedef __attribute__((ext_vector_type(8))) short bfrag;   // 8 bf16
typedef __attribute__((ext_vector_type(4))) float ffrag;   // 4 fp32
#define MFMA(a, b, c) __builtin_amdgcn_mfma_f32_16x16x32_bf16(a, b, c, 0, 0, 0)

__device__ __forceinline__ void gload16(const void* g, void* l) {
    __builtin_amdgcn_global_load_lds(
        (const __attribute__((address_space(1))) unsigned int*)g,
        (__attribute__((address_space(3))) unsigned int*)l, 16, 0, 0);
}

__device__ __forceinline__ unsigned f2bf(float f) {   // fp32 -> bf16 bits, RNE
    unsigned u = __float_as_uint(f);
    return (u + 0x7fffu + ((u >> 16) & 1u)) >> 16;
}

// padded row index for pixel n: (h+1)*66 + (w+1) = n + 2*(n>>6) + 67
__device__ __forceinline__ int prow(int n) { return n + 2 * (n >> 6) + 67; }

// ---------------------------------------------------------------------------
__global__ __launch_bounds__(256) void k_fill0(uint4* __restrict__ p) {
    uint4 z; z.x = z.y = z.z = z.w = 0u;
    p[(size_t)blockIdx.x * 256 + threadIdx.x] = z;
}

// w_top/w_cen [64][512] fp32 -> bf16 (layout kept: [p][i], K=i contiguous)
__global__ __launch_bounds__(256) void k_wpc(const float* __restrict__ wt,
        const float* __restrict__ wc, short* __restrict__ ot, short* __restrict__ oc) {
    const float* src = blockIdx.y ? wc : wt;
    short* dst       = blockIdx.y ? oc : ot;
    int idx = (blockIdx.x * 256 + threadIdx.x) * 4;
    float4 v = *(const float4*)(src + idx);
    uint2 u;
    u.x = f2bf(v.x) | (f2bf(v.y) << 16);
    u.y = f2bf(v.z) | (f2bf(v.w) << 16);
    *(uint2*)(dst + idx) = u;
}

// w [O][I][3][3] fp32 -> wT[k][o][i] bf16
__global__ __launch_bounds__(256) void k_w9(const float* __restrict__ wb,
        const float* __restrict__ wo, short* __restrict__ wbT, short* __restrict__ woT) {
    const float* w = blockIdx.z ? wo : wb;
    short* wT      = blockIdx.z ? woT : wbT;
    int o = blockIdx.x;
    int i = blockIdx.y * 256 + threadIdx.x;
    const float* src = w + ((size_t)o * CIN + i) * 9;
    float v[9];
#pragma unroll
    for (int k = 0; k < 9; k++) v[k] = src[k];
#pragma unroll
    for (int k = 0; k < 9; k++)
        wT[((size_t)k * CIN + o) * CIN + i] = (short)f2bf(v[k]);
}

// ---------------------------------------------------------------------------
// x [B][512][4096] fp32 (ADD: + invZ * O [n][c] fp32, raw-reshape-equivalent) ->
// pixel-major padded bf16 xp [B][4356][512]. Borders pre-zeroed by k_fill0.
// grid (64 pix-tiles, 8 ch-tiles, B)
template <bool ADD>
__global__ __launch_bounds__(256) void k_padT(const float* __restrict__ x,
        const float* __restrict__ Oc, const float* __restrict__ Zp,
        short* __restrict__ xp) {
    __shared__ float Ts[64][68];
    int t = threadIdx.x;
    int n0 = blockIdx.x * 64, c0 = blockIdx.y * 64, b = blockIdx.z;
    float iz = ADD ? (1.0f / Zp[b]) : 1.0f;
    const float* xb = x + ((size_t)b * CIN + c0) * HW;
#pragma unroll
    for (int j = 0; j < 4; j++) {
        int slot = j * 256 + t;
        int r = slot >> 4, col = (slot & 15) * 4;
        float4 v = *(const float4*)(xb + (size_t)r * HW + n0 + col);
        *(float4*)&Ts[r][col] = v;
    }
    __syncthreads();
    short* xpb = xp + (size_t)b * PROW * CIN;
    const float* ob = ADD ? (Oc + (size_t)b * HW * CIN) : nullptr;
#pragma unroll
    for (int j = 0; j < 2; j++) {
        int slot = j * 256 + t;
        int pix = slot >> 3, ch = (slot & 7) * 8;
        int rp = prow(n0 + pix);
        float v[8];
#pragma unroll
        for (int k = 0; k < 8; k++) v[k] = Ts[ch + k][pix];
        if (ADD) {
            const float* os = ob + (size_t)(n0 + pix) * CIN + c0 + ch;
#pragma unroll
            for (int k = 0; k < 8; k += 4) {
                float4 o4 = *(const float4*)(os + k);
                v[k]   += o4.x * iz; v[k+1] += o4.y * iz;
                v[k+2] += o4.z * iz; v[k+3] += o4.w * iz;
            }
        }
        unsigned pk[4];
#pragma unroll
        for (int k = 0; k < 4; k++)
            pk[k] = f2bf(v[2*k]) | (f2bf(v[2*k+1]) << 16);
        *(uint4*)(xpb + (size_t)rp * CIN + c0 + ch) = *(uint4*)pk;
    }
}

// ---------------------------------------------------------------------------
// 1x1 convs: xt/xc[n][p] = sum_i xp[n][i]*w[p][i] + bias.  M=p(64), N=n(64), K=512
// grid (64 n-tiles, 8: b*2+which)
__global__ __launch_bounds__(256) void k_qk(const short* __restrict__ xp,
        const short* __restrict__ wtop, const short* __restrict__ wcen,
        const float* __restrict__ btop, const float* __restrict__ bcen,
        short* __restrict__ xt, short* __restrict__ xc) {
    __shared__ __align__(16) short As[2048];   // w: 64 rows(p) x 32(i)
    __shared__ __align__(16) short Bs[2048];   // x: 64 rows(n) x 32(i)
    int t = threadIdx.x;
    int n0 = blockIdx.x * 64;
    int b = blockIdx.y >> 1, which = blockIdx.y & 1;
    const short* w    = which ? wcen : wtop;
    const float* bias = which ? bcen : btop;
    short* out        = (which ? xc : xt) + (size_t)b * HW * PABN;
    const short* xb   = xp + (size_t)b * PROW * CIN;

    int arow = t >> 2, ach = t & 3;
    int sch = ach ^ ((arow >> 1) & 3);
    int rp = prow(n0 + arow);
    int lane = t & 63, wid = t >> 6, l15 = lane & 15, q = lane >> 4;
    int wm = wid >> 1, wn = wid & 1;
    int cx = (q ^ ((l15 >> 1) & 3)) * 8;
    ffrag acc[2][2] = {};

    for (int i0 = 0; i0 < CIN; i0 += 32) {
        gload16(w  + (size_t)arow * CIN + i0 + sch * 8, As + t * 8);
        gload16(xb + (size_t)rp   * CIN + i0 + sch * 8, Bs + t * 8);
        __syncthreads();
        bfrag a[2], bb[2];
        a[0]  = *(const bfrag*)(As + (wm * 32 + l15) * 32 + cx);
        a[1]  = *(const bfrag*)(As + (wm * 32 + 16 + l15) * 32 + cx);
        bb[0] = *(const bfrag*)(Bs + (wn * 32 + l15) * 32 + cx);
        bb[1] = *(const bfrag*)(Bs + (wn * 32 + 16 + l15) * 32 + cx);
        acc[0][0] = MFMA(a[0], bb[0], acc[0][0]);
        acc[0][1] = MFMA(a[0], bb[1], acc[0][1]);
        acc[1][0] = MFMA(a[1], bb[0], acc[1][0]);
        acc[1][1] = MFMA(a[1], bb[1], acc[1][1]);
        __syncthreads();
    }
#pragma unroll
    for (int mi = 0; mi < 2; mi++) {
        int p = wm * 32 + mi * 16 + q * 4;
        float4 bv = *(const float4*)(bias + p);
#pragma unroll
        for (int ni = 0; ni < 2; ni++) {
            int nn = n0 + wn * 32 + ni * 16 + l15;
            ffrag v = acc[mi][ni];
            uint2 u;
            u.x = f2bf(v.x + bv.x) | (f2bf(v.y + bv.y) << 16);
            u.y = f2bf(v.z + bv.z) | (f2bf(v.w + bv.w) << 16);
            *(uint2*)(out + (size_t)nn * PABN + p) = u;
        }
    }
}

// ---------------------------------------------------------------------------
// conv3x3: out = conv(in, wT) + bias.  M=n(128), N=o(128), K=i over 9 taps.
// grid (32 n-tiles, 4 o-tiles, B)
template <bool FP32OUT>
__global__ __launch_bounds__(256) void k_conv(const short* __restrict__ xin,
        const short* __restrict__ wT, const float* __restrict__ bias,
        void* __restrict__ outv) {
    __shared__ __align__(16) short As[8192];   // pixels: 128 x 64
    __shared__ __align__(16) short Bs[8192];   // weights: 128(o) x 64
    int t = threadIdx.x;
    int n0 = blockIdx.x * 128, o0 = blockIdx.y * 128, b = blockIdx.z;
    const short* xb = xin + (size_t)b * PROW * CIN;
    int lane = t & 63, wid = t >> 6, l15 = lane & 15, q = lane >> 4;
    int wm = wid >> 1, wn = wid & 1;
    int arow = t >> 3, ach = t & 7;
    int sch = ach ^ (arow & 7);
    int pr[4];
#pragma unroll
    for (int j = 0; j < 4; j++) pr[j] = prow(n0 + j * 32 + arow);
    ffrag acc[4][4] = {};

    for (int k9 = 0; k9 < 9; k9++) {
        int kh = k9 / 3, kw = k9 - kh * 3;
        int sh = (kh - 1) * 66 + (kw - 1);
        const short* wk = wT + (size_t)k9 * CIN * CIN;
        for (int i0 = 0; i0 < CIN; i0 += 64) {
#pragma unroll
            for (int j = 0; j < 4; j++) {
                gload16(xb + (size_t)(pr[j] + sh) * CIN + i0 + sch * 8,
                        As + (j * 256 + t) * 8);
                gload16(wk + (size_t)(o0 + j * 32 + arow) * CIN + i0 + sch * 8,
                        Bs + (j * 256 + t) * 8);
            }
            __syncthreads();
#pragma unroll
            for (int kc = 0; kc < 2; kc++) {
                int cx = (((kc * 4 + q) ^ (l15 & 7))) * 8;
                bfrag a[4], bb[4];
#pragma unroll
                for (int mi = 0; mi < 4; mi++)
                    a[mi] = *(const bfrag*)(As + (wm * 64 + mi * 16 + l15) * 64 + cx);
#pragma unroll
                for (int ni = 0; ni < 4; ni++)
                    bb[ni] = *(const bfrag*)(Bs + (wn * 64 + ni * 16 + l15) * 64 + cx);
#pragma unroll
                for (int mi = 0; mi < 4; mi++)
#pragma unroll
                    for (int ni = 0; ni < 4; ni++)
                        acc[mi][ni] = MFMA(a[mi], bb[ni], acc[mi][ni]);
            }
            __syncthreads();
        }
    }
#pragma unroll
    for (int ni = 0; ni < 4; ni++) {
        int o = o0 + wn * 64 + ni * 16 + l15;
        float bv = bias[o];
#pragma unroll
        for (int mi = 0; mi < 4; mi++) {
            int n = n0 + wm * 64 + mi * 16 + q * 4;
            ffrag v = acc[mi][ni];
            if (FP32OUT) {
                float* out = (float*)outv + (size_t)b * CIN * HW;
                *(float4*)(out + (size_t)o * HW + n) =
                    make_float4(v.x + bv, v.y + bv, v.z + bv, v.w + bv);
            } else {
                short* out = (short*)outv + (size_t)b * CIN * HW;
                uint2 u;
                u.x = f2bf(v.x + bv) | (f2bf(v.y + bv) << 16);
                u.y = f2bf(v.z + bv) | (f2bf(v.w + bv) << 16);
                *(uint2*)(out + (size_t)o * HW + n) = u;
            }
        }
    }
}

// ---------------------------------------------------------------------------
// Fused S+PV v4: XB never touches LDS.  (resubmit x2 — rounds 4/5 were infra
// failures: container-start failure, then GPU-acquisition timeout; kernel
// never ran. Source unchanged to preserve the A/B vs v3 @128us.)
//   256-thr (4-wave) blocks, tile 64n x 256c, m-step 64.  Per iter:
//     top: issue XT(it+1) gload_lds x2 (stays in flight through S+exp)
//     S cluster: 8 MFMA (aS regs x XT[cur] LDS)
//     B1 -> exp -> PS (chunk-swizzled bf16) -> lgkmcnt(0) -> vmcnt(0) -> B2
//     PV cluster: av DIRECT from global/L2 (global_load_dwordx4, coalesced
//       16 rows x 64B), bv from PS; 32 MFMA.  av live range is inside the
//       un-pinned PV block only -> no cross-barrier spill (v2 lesson).
// LDS 24 KB: XT[2][64][64] dbuf | PS[64][64].  VGPR capped via launch_bounds.
// grid 512 XCD-chunked: each XCD owns one (b,chalf) slice -> xb L2-resident.
__global__ __launch_bounds__(256, 3) void k_fused(const short* __restrict__ xc,
        const short* __restrict__ xt, const short* __restrict__ xb,
        float* __restrict__ O, float* __restrict__ Zbuf) {
    __shared__ __align__(16) short SM[12288];   // 24576 B
    __shared__ float red[4];
    short* XT0 = SM;                  // [2][64][64]
    short* PS  = SM + 8192;           // [64][64]

    int bid = blockIdx.x;
    int wg = ((bid & 7) << 6) | (bid >> 3);     // XCD-chunked bijection (512%8==0)
    int b = wg >> 7, chalf = (wg >> 6) & 1, ntile = wg & 63;
    int n0 = ntile * 64, c0 = chalf * 256;
    const short* xcb = xc + (size_t)b * HW * PABN;
    const short* xtb = xt + (size_t)b * HW * PABN;
    const short* xbb = xb + (size_t)b * CIN * HW + (size_t)c0 * HW;

    int t = threadIdx.x;
    int lane = t & 63, wid = t >> 6, l15 = lane & 15, q = lane >> 4;
    int srow = t >> 3;                 // staging row 0..31
    int sch = (t & 7) ^ (srow & 7);    // pre-swizzled chunk (gload_lds path)

    // ---- prologue: XC -> PS area, XT(0) -> XT0[0] (swizzled via source)
    gload16(xcb + (size_t)(n0 + srow) * PABN + sch * 8, PS + t * 8);
    gload16(xcb + (size_t)(n0 + srow + 32) * PABN + sch * 8, PS + (256 + t) * 8);
    gload16(xtb + (size_t)srow * PABN + sch * 8, XT0 + t * 8);
    gload16(xtb + (size_t)(srow + 32) * PABN + sch * 8, XT0 + (256 + t) * 8);
    asm volatile("s_waitcnt vmcnt(0)" ::: "memory");
    __builtin_amdgcn_s_barrier();
    asm volatile("" ::: "memory");
    bfrag aS[2];                                // loop-invariant xc A-frags
#pragma unroll
    for (int kc = 0; kc < 2; kc++)
        aS[kc] = *(const bfrag*)(PS + (wid * 16 + l15) * 64
                                 + ((kc * 4 + q) ^ (l15 & 7)) * 8);
    asm volatile("s_waitcnt lgkmcnt(0)" ::: "memory");
    __builtin_amdgcn_s_barrier();               // PS now reusable
    asm volatile("" ::: "memory");

    ffrag acc[4][4] = {};
    float zacc = 0.f;
    int nrow = wid * 16 + q * 4;
    // per-lane base for direct-global PV A-frag loads: c-row = wid*64 + ci*16 + l15
    const short* avbase = xbb + (size_t)(wid * 64 + l15) * HW;

    for (int it = 0; it < 64; ++it) {
        const short* XTc = XT0 + (it & 1) * 4096;
        if (it < 63) {                          // prefetch next XT tile
            int m1 = (it + 1) * 64, nxt = (it & 1) ^ 1;
            gload16(xtb + (size_t)(m1 + srow) * PABN + sch * 8,
                    XT0 + nxt * 4096 + t * 8);
            gload16(xtb + (size_t)(m1 + srow + 32) * PABN + sch * 8,
                    XT0 + nxt * 4096 + (256 + t) * 8);
        }
        // ---- S cluster: S[n=nrow..][m=it*64..]
        ffrag s[4] = {};
        __builtin_amdgcn_s_setprio(1);
#pragma unroll
        for (int ni = 0; ni < 4; ni++)
#pragma unroll
            for (int kc = 0; kc < 2; kc++) {
                bfrag bf = *(const bfrag*)(XTc + (ni * 16 + l15) * 64
                                           + ((kc * 4 + q) ^ (l15 & 7)) * 8);
                s[ni] = MFMA(aS[kc], bf, s[ni]);
            }
        __builtin_amdgcn_s_setprio(0);
        __builtin_amdgcn_s_barrier();           // B1: PV(it-1) PS-reads all done
        asm volatile("" ::: "memory");
        // ---- exp + PS(it) write (chunk-swizzled)
#pragma unroll
        for (int ni = 0; ni < 4; ni++) {
            int cc = ni * 2 + (l15 >> 3), jj = l15 & 7;
#pragma unroll
            for (int r = 0; r < 4; r++) {
                float e = __expf(s[ni][r]);
                zacc += e;
                PS[(nrow + r) * 64 + (cc ^ ((nrow + r) & 7)) * 8 + jj] =
                    (short)f2bf(e);
            }
        }
        asm volatile("s_waitcnt vmcnt(0) lgkmcnt(0)" ::: "memory"); // XT(it+1)+PS in
        __builtin_amdgcn_s_barrier();           // B2: publishes PS(it), XT(it+1)
        asm volatile("" ::: "memory");
        // ---- PV cluster: acc[c][n] += xb[c][m-tile] . P^T, av direct from L2
        __builtin_amdgcn_s_setprio(1);
#pragma unroll
        for (int kc = 0; kc < 2; kc++) {
            int cx = ((kc * 4 + q) ^ (l15 & 7)) * 8;
            int mg = it * 64 + (kc * 4 + q) * 8;     // linear global m offset
            bfrag av[4], bv[4];
#pragma unroll
            for (int ci = 0; ci < 4; ci++)
                av[ci] = *(const bfrag*)(avbase + (size_t)(ci * 16) * HW + mg);
#pragma unroll
            for (int nj = 0; nj < 4; nj++)
                bv[nj] = *(const bfrag*)(PS + (nj * 16 + l15) * 64 + cx);
#pragma unroll
            for (int ci = 0; ci < 4; ci++)
#pragma unroll
                for (int nj = 0; nj < 4; nj++)
                    acc[ci][nj] = MFMA(av[ci], bv[nj], acc[ci][nj]);
        }
        __builtin_amdgcn_s_setprio(0);
    }
    // ---- z reduce (chalf 0 blocks only; both halves computed identical S)
#pragma unroll
    for (int off = 32; off > 0; off >>= 1) zacc += __shfl_down(zacc, off, 64);
    __syncthreads();                            // last PV PS-reads done
    if (lane == 0) red[wid] = zacc;
    __syncthreads();
    if (chalf == 0 && t == 0)
        Zbuf[b * 64 + ntile] = red[0] + red[1] + red[2] + red[3];
    // ---- O store (unscaled fp32, [n][c]; invZ applied in k_padT<true>)
    float* Ob = O + (size_t)b * HW * CIN;
#pragma unroll
    for (int ci = 0; ci < 4; ci++)
#pragma unroll
        for (int nj = 0; nj < 4; nj++) {
            int n = n0 + nj * 16 + l15;
            int c = c0 + wid * 64 + ci * 16 + q * 4;
            ffrag v = acc[ci][nj];
            *(float4*)(Ob + (size_t)n * CIN + c) =
                make_float4(v.x, v.y, v.z, v.w);
        }
}

// ---------------------------------------------------------------------------
// Reduce Zbuf[b][0..63] -> Z[b]. 1 block, 256 thr (wave per batch).
__global__ __launch_bounds__(256) void k_redz(const float* __restrict__ Zbuf,
        float* __restrict__ Z) {
    int wid = threadIdx.x >> 6, lane = threadIdx.x & 63;
    float s = Zbuf[wid * 64 + lane];
#pragma unroll
    for (int off = 32; off > 0; off >>= 1) s += __shfl_down(s, off, 64);
    if (lane == 0) Z[wid] = s;
}

// ---------------------------------------------------------------------------
extern "C" void kernel_launch(void* const* d_in, const int* in_sizes, int n_in,
                              void* d_out, int out_size, void* d_ws, size_t ws_size,
                              hipStream_t stream) {
    const float* x     = (const float*)d_in[0];
    const float* w_top = (const float*)d_in[1];
    const float* b_top = (const float*)d_in[2];
    const float* w_cen = (const float*)d_in[3];
    const float* b_cen = (const float*)d_in[4];
    const float* w_bot = (const float*)d_in[5];
    const float* b_bot = (const float*)d_in[6];
    const float* w_out = (const float*)d_in[7];
    const float* b_out = (const float*)d_in[8];

    char* W = (char*)d_ws;
    short* xp   = (short*)(W);               // 17,842,176 B (also reused as yp)
    short* xt   = (short*)(W + 17842176);    //  2,097,152
    short* xc   = (short*)(W + 19939328);    //  2,097,152
    short* wtb  = (short*)(W + 22036480);    //     65,536
    short* wcb  = (short*)(W + 22102016);    //     65,536
    short* wbT  = (short*)(W + 22167552);    //  4,718,592
    short* woT  = (short*)(W + 26886144);    //  4,718,592
    short* xbc  = (short*)(W + 31604736);    // 16,777,216
    float* O    = (float*)(W + 48381952);    // 33,554,432 (unscaled PV output)
    float* Z    = (float*)(W + 81936384);    //        512
    float* Zbuf = (float*)(W + 81936896);    //     16,384 (uses 256 floats)

    k_fill0<<<4356, 256, 0, stream>>>((uint4*)xp);           // zero padded buffer
    k_wpc<<<dim3(32, 2), 256, 0, stream>>>(w_top, w_cen, wtb, wcb);
    k_w9<<<dim3(512, 2, 2), 256, 0, stream>>>(w_bot, w_out, wbT, woT);
    k_padT<false><<<dim3(64, 8, BATCH), 256, 0, stream>>>(x, nullptr, nullptr, xp);
    k_qk<<<dim3(64, 8), 256, 0, stream>>>(xp, wtb, wcb, b_top, b_cen, xt, xc);
    k_conv<false><<<dim3(32, 4, BATCH), 256, 0, stream>>>(xp, wbT, b_bot, xbc);
    k_fused<<<dim3(512), 256, 0, stream>>>(xc, xt, xbc, O, Zbuf);
    k_redz<<<1, 256, 0, stream>>>(Zbuf, Z);
    k_padT<true><<<dim3(64, 8, BATCH), 256, 0, stream>>>(x, O, Z, xp);  // y -> xp
    k_conv<true><<<dim3(32, 4, BATCH), 256, 0, stream>>>(xp, woT, b_out, (float*)d_out);
}

// Round 7
// 424.099 us; speedup vs baseline: 1.1358x; 1.1358x over previous
//
#include <hip/hip_runtime.h>
#include <math.h>

#define BATCH 4
#define CIN   512
#define PABN  64
#define HW    4096
#define PROW  4356            // 66*66 padded pixel rows

typedef __attribute__((ext_vector_type(8))) short bfrag;   // 8 bf16
typedef __attribute__((ext_vector_type(4))) float ffrag;   // 4 fp32
#define MFMA(a, b, c) __builtin_amdgcn_mfma_f32_16x16x32_bf16(a, b, c, 0, 0, 0)

__device__ __forceinline__ void gload16(const void* g, void* l) {
    __builtin_amdgcn_global_load_lds(
        (const __attribute__((address_space(1))) unsigned int*)g,
        (__attribute__((address_space(3))) unsigned int*)l, 16, 0, 0);
}

__device__ __forceinline__ unsigned f2bf(float f) {   // fp32 -> bf16 bits, RNE
    unsigned u = __float_as_uint(f);
    return (u + 0x7fffu + ((u >> 16) & 1u)) >> 16;
}

// padded row index for pixel n: (h+1)*66 + (w+1) = n + 2*(n>>6) + 67
__device__ __forceinline__ int prow(int n) { return n + 2 * (n >> 6) + 67; }

// ---------------------------------------------------------------------------
__global__ __launch_bounds__(256) void k_fill0(uint4* __restrict__ p) {
    uint4 z; z.x = z.y = z.z = z.w = 0u;
    p[(size_t)blockIdx.x * 256 + threadIdx.x] = z;
}

// w_top/w_cen [64][512] fp32 -> bf16 (layout kept: [p][i], K=i contiguous)
__global__ __launch_bounds__(256) void k_wpc(const float* __restrict__ wt,
        const float* __restrict__ wc, short* __restrict__ ot, short* __restrict__ oc) {
    const float* src = blockIdx.y ? wc : wt;
    short* dst       = blockIdx.y ? oc : ot;
    int idx = (blockIdx.x * 256 + threadIdx.x) * 4;
    float4 v = *(const float4*)(src + idx);
    uint2 u;
    u.x = f2bf(v.x) | (f2bf(v.y) << 16);
    u.y = f2bf(v.z) | (f2bf(v.w) << 16);
    *(uint2*)(dst + idx) = u;
}

// w [O][I][3][3] fp32 -> wT[k][o][i] bf16
__global__ __launch_bounds__(256) void k_w9(const float* __restrict__ wb,
        const float* __restrict__ wo, short* __restrict__ wbT, short* __restrict__ woT) {
    const float* w = blockIdx.z ? wo : wb;
    short* wT      = blockIdx.z ? woT : wbT;
    int o = blockIdx.x;
    int i = blockIdx.y * 256 + threadIdx.x;
    const float* src = w + ((size_t)o * CIN + i) * 9;
    float v[9];
#pragma unroll
    for (int k = 0; k < 9; k++) v[k] = src[k];
#pragma unroll
    for (int k = 0; k < 9; k++)
        wT[((size_t)k * CIN + o) * CIN + i] = (short)f2bf(v[k]);
}

// ---------------------------------------------------------------------------
// x [B][512][4096] fp32 (ADD: + invZ * O [n][c] fp32, raw-reshape-equivalent) ->
// pixel-major padded bf16 xp [B][4356][512]. Borders pre-zeroed by k_fill0.
// grid (64 pix-tiles, 8 ch-tiles, B)
template <bool ADD>
__global__ __launch_bounds__(256) void k_padT(const float* __restrict__ x,
        const float* __restrict__ Oc, const float* __restrict__ Zp,
        short* __restrict__ xp) {
    __shared__ float Ts[64][68];
    int t = threadIdx.x;
    int n0 = blockIdx.x * 64, c0 = blockIdx.y * 64, b = blockIdx.z;
    float iz = ADD ? (1.0f / Zp[b]) : 1.0f;
    const float* xb = x + ((size_t)b * CIN + c0) * HW;
#pragma unroll
    for (int j = 0; j < 4; j++) {
        int slot = j * 256 + t;
        int r = slot >> 4, col = (slot & 15) * 4;
        float4 v = *(const float4*)(xb + (size_t)r * HW + n0 + col);
        *(float4*)&Ts[r][col] = v;
    }
    __syncthreads();
    short* xpb = xp + (size_t)b * PROW * CIN;
    const float* ob = ADD ? (Oc + (size_t)b * HW * CIN) : nullptr;
#pragma unroll
    for (int j = 0; j < 2; j++) {
        int slot = j * 256 + t;
        int pix = slot >> 3, ch = (slot & 7) * 8;
        int rp = prow(n0 + pix);
        float v[8];
#pragma unroll
        for (int k = 0; k < 8; k++) v[k] = Ts[ch + k][pix];
        if (ADD) {
            const float* os = ob + (size_t)(n0 + pix) * CIN + c0 + ch;
#pragma unroll
            for (int k = 0; k < 8; k += 4) {
                float4 o4 = *(const float4*)(os + k);
                v[k]   += o4.x * iz; v[k+1] += o4.y * iz;
                v[k+2] += o4.z * iz; v[k+3] += o4.w * iz;
            }
        }
        unsigned pk[4];
#pragma unroll
        for (int k = 0; k < 4; k++)
            pk[k] = f2bf(v[2*k]) | (f2bf(v[2*k+1]) << 16);
        *(uint4*)(xpb + (size_t)rp * CIN + c0 + ch) = *(uint4*)pk;
    }
}

// ---------------------------------------------------------------------------
// 1x1 convs: xt/xc[n][p] = sum_i xp[n][i]*w[p][i] + bias.  M=p(64), N=n(64), K=512
// grid (64 n-tiles, 8: b*2+which)
__global__ __launch_bounds__(256) void k_qk(const short* __restrict__ xp,
        const short* __restrict__ wtop, const short* __restrict__ wcen,
        const float* __restrict__ btop, const float* __restrict__ bcen,
        short* __restrict__ xt, short* __restrict__ xc) {
    __shared__ __align__(16) short As[2048];   // w: 64 rows(p) x 32(i)
    __shared__ __align__(16) short Bs[2048];   // x: 64 rows(n) x 32(i)
    int t = threadIdx.x;
    int n0 = blockIdx.x * 64;
    int b = blockIdx.y >> 1, which = blockIdx.y & 1;
    const short* w    = which ? wcen : wtop;
    const float* bias = which ? bcen : btop;
    short* out        = (which ? xc : xt) + (size_t)b * HW * PABN;
    const short* xb   = xp + (size_t)b * PROW * CIN;

    int arow = t >> 2, ach = t & 3;
    int sch = ach ^ ((arow >> 1) & 3);
    int rp = prow(n0 + arow);
    int lane = t & 63, wid = t >> 6, l15 = lane & 15, q = lane >> 4;
    int wm = wid >> 1, wn = wid & 1;
    int cx = (q ^ ((l15 >> 1) & 3)) * 8;
    ffrag acc[2][2] = {};

    for (int i0 = 0; i0 < CIN; i0 += 32) {
        gload16(w  + (size_t)arow * CIN + i0 + sch * 8, As + t * 8);
        gload16(xb + (size_t)rp   * CIN + i0 + sch * 8, Bs + t * 8);
        __syncthreads();
        bfrag a[2], bb[2];
        a[0]  = *(const bfrag*)(As + (wm * 32 + l15) * 32 + cx);
        a[1]  = *(const bfrag*)(As + (wm * 32 + 16 + l15) * 32 + cx);
        bb[0] = *(const bfrag*)(Bs + (wn * 32 + l15) * 32 + cx);
        bb[1] = *(const bfrag*)(Bs + (wn * 32 + 16 + l15) * 32 + cx);
        acc[0][0] = MFMA(a[0], bb[0], acc[0][0]);
        acc[0][1] = MFMA(a[0], bb[1], acc[0][1]);
        acc[1][0] = MFMA(a[1], bb[0], acc[1][0]);
        acc[1][1] = MFMA(a[1], bb[1], acc[1][1]);
        __syncthreads();
    }
#pragma unroll
    for (int mi = 0; mi < 2; mi++) {
        int p = wm * 32 + mi * 16 + q * 4;
        float4 bv = *(const float4*)(bias + p);
#pragma unroll
        for (int ni = 0; ni < 2; ni++) {
            int nn = n0 + wn * 32 + ni * 16 + l15;
            ffrag v = acc[mi][ni];
            uint2 u;
            u.x = f2bf(v.x + bv.x) | (f2bf(v.y + bv.y) << 16);
            u.y = f2bf(v.z + bv.z) | (f2bf(v.w + bv.w) << 16);
            *(uint2*)(out + (size_t)nn * PABN + p) = u;
        }
    }
}

// ---------------------------------------------------------------------------
// conv3x3 v2 (T3-lite): single barrier per K-step, LDS double-buffered,
// stage(ks+1) issued BEFORE compute(ks), vmcnt(0) drained AFTER the MFMA
// cluster. 72 flat K-steps (9 taps x 8 chunks) -> pipeline never drains at
// tap boundaries. LDS 64KB -> 2 blocks/CU (grid 512 = 2 resident/CU).
// M=n(128), N=o(128). grid (32 n-tiles, 4 o-tiles, B)
template <bool FP32OUT>
__global__ __launch_bounds__(256) void k_conv(const short* __restrict__ xin,
        const short* __restrict__ wT, const float* __restrict__ bias,
        void* __restrict__ outv) {
    __shared__ __align__(16) short As[2][8192];   // pixels: 128 x 64
    __shared__ __align__(16) short Bs[2][8192];   // weights: 128(o) x 64
    int t = threadIdx.x;
    int n0 = blockIdx.x * 128, o0 = blockIdx.y * 128, b = blockIdx.z;
    const short* xb = xin + (size_t)b * PROW * CIN;
    int lane = t & 63, wid = t >> 6, l15 = lane & 15, q = lane >> 4;
    int wm = wid >> 1, wn = wid & 1;
    int arow = t >> 3, ach = t & 7;
    int sch = ach ^ (arow & 7);
    int pr[4];
#pragma unroll
    for (int j = 0; j < 4; j++) pr[j] = prow(n0 + j * 32 + arow);
    ffrag acc[4][4] = {};

    auto stage = [&](int ks, int bsel) {
        int k9 = ks >> 3, i0 = (ks & 7) << 6;
        int kh = k9 / 3, kw = k9 - kh * 3;
        int sh = (kh - 1) * 66 + (kw - 1);
        const short* wk = wT + (size_t)k9 * CIN * CIN;
#pragma unroll
        for (int j = 0; j < 4; j++) {
            gload16(xb + (size_t)(pr[j] + sh) * CIN + i0 + sch * 8,
                    &As[bsel][(j * 256 + t) * 8]);
            gload16(wk + (size_t)(o0 + j * 32 + arow) * CIN + i0 + sch * 8,
                    &Bs[bsel][(j * 256 + t) * 8]);
        }
    };

    stage(0, 0);
    asm volatile("s_waitcnt vmcnt(0)" ::: "memory");
    __builtin_amdgcn_s_barrier();
    asm volatile("" ::: "memory");

    for (int ks = 0; ks < 72; ++ks) {
        int cur = ks & 1;
        if (ks < 71) stage(ks + 1, cur ^ 1);   // issue next-step loads first
        __builtin_amdgcn_s_setprio(1);
#pragma unroll
        for (int kc = 0; kc < 2; kc++) {
            int cx = (((kc * 4 + q) ^ (l15 & 7))) * 8;
            bfrag a[4], bb[4];
#pragma unroll
            for (int mi = 0; mi < 4; mi++)
                a[mi] = *(const bfrag*)(&As[cur][(wm * 64 + mi * 16 + l15) * 64 + cx]);
#pragma unroll
            for (int ni = 0; ni < 4; ni++)
                bb[ni] = *(const bfrag*)(&Bs[cur][(wn * 64 + ni * 16 + l15) * 64 + cx]);
#pragma unroll
            for (int mi = 0; mi < 4; mi++)
#pragma unroll
                for (int ni = 0; ni < 4; ni++)
                    acc[mi][ni] = MFMA(a[mi], bb[ni], acc[mi][ni]);
        }
        __builtin_amdgcn_s_setprio(0);
        asm volatile("s_waitcnt vmcnt(0)" ::: "memory");   // next tile landed
        __builtin_amdgcn_s_barrier();                      // publish; reads done
        asm volatile("" ::: "memory");
    }
#pragma unroll
    for (int ni = 0; ni < 4; ni++) {
        int o = o0 + wn * 64 + ni * 16 + l15;
        float bv = bias[o];
#pragma unroll
        for (int mi = 0; mi < 4; mi++) {
            int n = n0 + wm * 64 + mi * 16 + q * 4;
            ffrag v = acc[mi][ni];
            if (FP32OUT) {
                float* out = (float*)outv + (size_t)b * CIN * HW;
                *(float4*)(out + (size_t)o * HW + n) =
                    make_float4(v.x + bv, v.y + bv, v.z + bv, v.w + bv);
            } else {
                short* out = (short*)outv + (size_t)b * CIN * HW;
                uint2 u;
                u.x = f2bf(v.x + bv) | (f2bf(v.y + bv) << 16);
                u.y = f2bf(v.z + bv) | (f2bf(v.w + bv) << 16);
                *(uint2*)(out + (size_t)o * HW + n) = u;
            }
        }
    }
}

// ---------------------------------------------------------------------------
// Fused S+PV (v1 RESTORED — measured 121.8us; v4's direct-global PV regressed
// to 201us from exposed L2 latency inside the MFMA cluster):
//   per block: n-tile 128, c-half 256, one batch. Loop m over 4096 step 64:
//     S[128n][64m] = xc.xt^T -> exp -> P in LDS (chunk-swizzled)
//     O[c][n] += xb[c][m-tile] . P^T   (acc VGPR, unscaled; invZ in k_padT)
// 8 waves (512 thr), 1 block/CU, grid 256 XCD-swizzled. LDS 112 KB:
//   XC[128][64] persistent | XT[2][64][64] dbuf | XB[2][256][64] dbuf | PS
// Raw s_barrier + counted vmcnt keeps 5 staging loads in flight across barriers.
__global__ __launch_bounds__(512) void k_fused(const short* __restrict__ xc,
        const short* __restrict__ xt, const short* __restrict__ xb,
        float* __restrict__ O, float* __restrict__ Zbuf) {
    __shared__ __align__(16) short SM[57344];   // 112 KB
    __shared__ float red[8];
    short* XC  = SM;                 // [128][64]
    short* XT0 = SM + 8192;          // [2][64][64]
    short* XB0 = SM + 16384;         // [2][256][64]
    short* PS  = SM + 49152;         // [128][64]

    int wg = ((blockIdx.x & 7) << 5) | (blockIdx.x >> 3);   // XCD-contiguous
    int b = wg >> 6, chalf = (wg >> 5) & 1, ntile = wg & 31;
    int n0 = ntile * 128, c0 = chalf * 256;
    const short* xcb = xc + (size_t)b * HW * PABN;
    const short* xtb = xt + (size_t)b * HW * PABN;
    const short* xbb = xb + (size_t)b * CIN * HW;

    int t = threadIdx.x;
    int lane = t & 63, wid = t >> 6, l15 = lane & 15, q = lane >> 4;
    int srow = t >> 3, sch = (t & 7) ^ (srow & 7);   // staging row / swizzled chunk
    int wc = wid >> 1, wnn = wid & 1;                // PV wave roles: c-quarter, n-half

    // prologue: persistent xc tile + step-0 xt/xb
    {
        const short* s0 = xcb + (size_t)(n0 + srow) * PABN + sch * 8;
        gload16(s0, XC + t * 8);
        gload16(s0 + 64 * PABN, XC + 4096 + t * 8);
        gload16(xtb + (size_t)srow * PABN + sch * 8, XT0 + t * 8);
#pragma unroll
        for (int p = 0; p < 4; p++)
            gload16(xbb + (size_t)(c0 + p * 64 + srow) * HW + sch * 8,
                    XB0 + (p * 512 + t) * 8);
    }
    asm volatile("s_waitcnt vmcnt(0)" ::: "memory");
    __builtin_amdgcn_s_barrier();
    asm volatile("" ::: "memory");

    // xc A-fragments are loop-invariant: hoist (wave wid owns S rows [wid*16,+16))
    bfrag aS[2];
#pragma unroll
    for (int kc = 0; kc < 2; kc++)
        aS[kc] = *(const bfrag*)(XC + (wid * 16 + l15) * 64
                                 + ((kc * 4 + q) ^ (l15 & 7)) * 8);

    ffrag acc[4][4] = {};
    float zacc = 0.f;

    for (int it = 0; it < 64; ++it) {
        int cur = it & 1;
        const short* XTc = XT0 + cur * 4096;
        const short* XBc = XB0 + cur * 16384;
        if (it < 63) {                       // issue next-step staging, keep in flight
            int m1 = (it + 1) * 64, nxt = cur ^ 1;
            gload16(xtb + (size_t)(m1 + srow) * PABN + sch * 8,
                    XT0 + nxt * 4096 + t * 8);
#pragma unroll
            for (int p = 0; p < 4; p++)
                gload16(xbb + (size_t)(c0 + p * 64 + srow) * HW + m1 + sch * 8,
                        XB0 + nxt * 16384 + (p * 512 + t) * 8);
            asm volatile("s_waitcnt vmcnt(5)" ::: "memory");   // wait prev group only
        } else {
            asm volatile("s_waitcnt vmcnt(0)" ::: "memory");
        }
        __builtin_amdgcn_s_barrier();
        asm volatile("" ::: "memory");

        // ---- S phase: wave wid computes S rows [wid*16,+16) x m[0,64)
        ffrag s[4] = {};
        __builtin_amdgcn_s_setprio(1);
#pragma unroll
        for (int ni = 0; ni < 4; ni++)
#pragma unroll
            for (int kc = 0; kc < 2; kc++) {
                bfrag bf = *(const bfrag*)(XTc + (ni * 16 + l15) * 64
                                           + ((kc * 4 + q) ^ (l15 & 7)) * 8);
                s[ni] = MFMA(aS[kc], bf, s[ni]);
            }
        __builtin_amdgcn_s_setprio(0);
        // exp + write P (bf16) chunk-swizzled: logical chunk cc at pos cc^(row&7)
        int nrow = wid * 16 + q * 4;
#pragma unroll
        for (int ni = 0; ni < 4; ni++) {
            int cc = ni * 2 + (l15 >> 3), j = l15 & 7;
#pragma unroll
            for (int r = 0; r < 4; r++) {
                float e = __expf(s[ni][r]);
                zacc += e;
                PS[(nrow + r) * 64 + (cc ^ ((nrow + r) & 7)) * 8 + j] =
                    (short)f2bf(e);
            }
        }
        asm volatile("s_waitcnt lgkmcnt(0)" ::: "memory");
        __builtin_amdgcn_s_barrier();
        asm volatile("" ::: "memory");

        // ---- PV phase: acc[c][n] += xb . P^T  (wave: c 64 x n 64)
        __builtin_amdgcn_s_setprio(1);
#pragma unroll
        for (int kc = 0; kc < 2; kc++) {
            int cx = ((kc * 4 + q) ^ (l15 & 7)) * 8;
            bfrag av[4], bv[4];
#pragma unroll
            for (int ci = 0; ci < 4; ci++)
                av[ci] = *(const bfrag*)(XBc + (wc * 64 + ci * 16 + l15) * 64 + cx);
#pragma unroll
            for (int nj = 0; nj < 4; nj++)
                bv[nj] = *(const bfrag*)(PS + (wnn * 64 + nj * 16 + l15) * 64 + cx);
#pragma unroll
            for (int ci = 0; ci < 4; ci++)
#pragma unroll
                for (int nj = 0; nj < 4; nj++)
                    acc[ci][nj] = MFMA(av[ci], bv[nj], acc[ci][nj]);
        }
        __builtin_amdgcn_s_setprio(0);
        asm volatile("" ::: "memory");
        __builtin_amdgcn_s_barrier();
        asm volatile("" ::: "memory");
    }

    // ---- z reduce (chalf 0 only contributes; both halves computed same S)
#pragma unroll
    for (int off = 32; off > 0; off >>= 1) zacc += __shfl_down(zacc, off, 64);
    if (lane == 0) red[wid] = zacc;
    __syncthreads();
    if (chalf == 0 && t == 0) {
        float z = 0.f;
#pragma unroll
        for (int i = 0; i < 8; i++) z += red[i];
        Zbuf[b * 32 + ntile] = z;
    }
    // ---- O store (unscaled fp32, [n][c])
    float* Ob = O + (size_t)b * HW * CIN;
#pragma unroll
    for (int ci = 0; ci < 4; ci++)
#pragma unroll
        for (int nj = 0; nj < 4; nj++) {
            int n = n0 + wnn * 64 + nj * 16 + l15;
            int c = c0 + wc * 64 + ci * 16 + q * 4;
            ffrag v = acc[ci][nj];
            *(float4*)(Ob + (size_t)n * CIN + c) =
                make_float4(v.x, v.y, v.z, v.w);
        }
}

// ---------------------------------------------------------------------------
// Reduce Zbuf[b][0..31] -> Z[b]. 1 block, 256 thr (wave per batch).
__global__ __launch_bounds__(256) void k_redz(const float* __restrict__ Zbuf,
        float* __restrict__ Z) {
    int wid = threadIdx.x >> 6, lane = threadIdx.x & 63;
    float s = (lane < 32) ? Zbuf[wid * 32 + lane] : 0.f;
#pragma unroll
    for (int off = 32; off > 0; off >>= 1) s += __shfl_down(s, off, 64);
    if (lane == 0) Z[wid] = s;
}

// ---------------------------------------------------------------------------
extern "C" void kernel_launch(void* const* d_in, const int* in_sizes, int n_in,
                              void* d_out, int out_size, void* d_ws, size_t ws_size,
                              hipStream_t stream) {
    const float* x     = (const float*)d_in[0];
    const float* w_top = (const float*)d_in[1];
    const float* b_top = (const float*)d_in[2];
    const float* w_cen = (const float*)d_in[3];
    const float* b_cen = (const float*)d_in[4];
    const float* w_bot = (const float*)d_in[5];
    const float* b_bot = (const float*)d_in[6];
    const float* w_out = (const float*)d_in[7];
    const float* b_out = (const float*)d_in[8];

    char* W = (char*)d_ws;
    short* xp   = (short*)(W);               // 17,842,176 B (also reused as yp)
    short* xt   = (short*)(W + 17842176);    //  2,097,152
    short* xc   = (short*)(W + 19939328);    //  2,097,152
    short* wtb  = (short*)(W + 22036480);    //     65,536
    short* wcb  = (short*)(W + 22102016);    //     65,536
    short* wbT  = (short*)(W + 22167552);    //  4,718,592
    short* woT  = (short*)(W + 26886144);    //  4,718,592
    short* xbc  = (short*)(W + 31604736);    // 16,777,216
    float* O    = (float*)(W + 48381952);    // 33,554,432 (unscaled PV output)
    float* Z    = (float*)(W + 81936384);    //        512
    float* Zbuf = (float*)(W + 81936896);    //     16,384 (uses 128 floats)

    k_fill0<<<4356, 256, 0, stream>>>((uint4*)xp);           // zero padded buffer
    k_wpc<<<dim3(32, 2), 256, 0, stream>>>(w_top, w_cen, wtb, wcb);
    k_w9<<<dim3(512, 2, 2), 256, 0, stream>>>(w_bot, w_out, wbT, woT);
    k_padT<false><<<dim3(64, 8, BATCH), 256, 0, stream>>>(x, nullptr, nullptr, xp);
    k_qk<<<dim3(64, 8), 256, 0, stream>>>(xp, wtb, wcb, b_top, b_cen, xt, xc);
    k_conv<false><<<dim3(32, 4, BATCH), 256, 0, stream>>>(xp, wbT, b_bot, xbc);
    k_fused<<<dim3(256), 512, 0, stream>>>(xc, xt, xbc, O, Zbuf);
    k_redz<<<1, 256, 0, stream>>>(Zbuf, Z);
    k_padT<true><<<dim3(64, 8, BATCH), 256, 0, stream>>>(x, O, Z, xp);  // y -> xp
    k_conv<true><<<dim3(32, 4, BATCH), 256, 0, stream>>>(xp, woT, b_out, (float*)d_out);
}

// Round 8
// 389.323 us; speedup vs baseline: 1.2372x; 1.0893x over previous
//
#include <hip/hip_runtime.h>
#include <math.h>

#define BATCH 4
#define CIN   512
#define PABN  64
#define HW    4096
#define PROW  4356            // 66*66 padded pixel rows

typedef __attribute__((ext_vector_type(8))) short bfrag;   // 8 bf16
typedef __attribute__((ext_vector_type(4))) float ffrag;   // 4 fp32
#define MFMA(a, b, c) __builtin_amdgcn_mfma_f32_16x16x32_bf16(a, b, c, 0, 0, 0)

__device__ __forceinline__ void gload16(const void* g, void* l) {
    __builtin_amdgcn_global_load_lds(
        (const __attribute__((address_space(1))) unsigned int*)g,
        (__attribute__((address_space(3))) unsigned int*)l, 16, 0, 0);
}

__device__ __forceinline__ unsigned f2bf(float f) {   // fp32 -> bf16 bits, RNE
    unsigned u = __float_as_uint(f);
    return (u + 0x7fffu + ((u >> 16) & 1u)) >> 16;
}

// padded row index for pixel n: (h+1)*66 + (w+1) = n + 2*(n>>6) + 67
__device__ __forceinline__ int prow(int n) { return n + 2 * (n >> 6) + 67; }

// ---------------------------------------------------------------------------
__global__ __launch_bounds__(256) void k_fill0(uint4* __restrict__ p) {
    uint4 z; z.x = z.y = z.z = z.w = 0u;
    p[(size_t)blockIdx.x * 256 + threadIdx.x] = z;
}

// w_top/w_cen [64][512] fp32 -> bf16 (layout kept: [p][i], K=i contiguous)
__global__ __launch_bounds__(256) void k_wpc(const float* __restrict__ wt,
        const float* __restrict__ wc, short* __restrict__ ot, short* __restrict__ oc) {
    const float* src = blockIdx.y ? wc : wt;
    short* dst       = blockIdx.y ? oc : ot;
    int idx = (blockIdx.x * 256 + threadIdx.x) * 4;
    float4 v = *(const float4*)(src + idx);
    uint2 u;
    u.x = f2bf(v.x) | (f2bf(v.y) << 16);
    u.y = f2bf(v.z) | (f2bf(v.w) << 16);
    *(uint2*)(dst + idx) = u;
}

// w [O][I][3][3] fp32 -> wT[k][o][i] bf16
__global__ __launch_bounds__(256) void k_w9(const float* __restrict__ wb,
        const float* __restrict__ wo, short* __restrict__ wbT, short* __restrict__ woT) {
    const float* w = blockIdx.z ? wo : wb;
    short* wT      = blockIdx.z ? woT : wbT;
    int o = blockIdx.x;
    int i = blockIdx.y * 256 + threadIdx.x;
    const float* src = w + ((size_t)o * CIN + i) * 9;
    float v[9];
#pragma unroll
    for (int k = 0; k < 9; k++) v[k] = src[k];
#pragma unroll
    for (int k = 0; k < 9; k++)
        wT[((size_t)k * CIN + o) * CIN + i] = (short)f2bf(v[k]);
}

// ---------------------------------------------------------------------------
// x [B][512][4096] fp32 (ADD: + invZ * O [n][c] fp32, raw-reshape-equivalent) ->
// pixel-major padded bf16 xp [B][4356][512]. Borders pre-zeroed by k_fill0.
// grid (64 pix-tiles, 8 ch-tiles, B)
template <bool ADD>
__global__ __launch_bounds__(256) void k_padT(const float* __restrict__ x,
        const float* __restrict__ Oc, const float* __restrict__ Zp,
        short* __restrict__ xp) {
    __shared__ float Ts[64][68];
    int t = threadIdx.x;
    int n0 = blockIdx.x * 64, c0 = blockIdx.y * 64, b = blockIdx.z;
    float iz = ADD ? (1.0f / Zp[b]) : 1.0f;
    const float* xb = x + ((size_t)b * CIN + c0) * HW;
#pragma unroll
    for (int j = 0; j < 4; j++) {
        int slot = j * 256 + t;
        int r = slot >> 4, col = (slot & 15) * 4;
        float4 v = *(const float4*)(xb + (size_t)r * HW + n0 + col);
        *(float4*)&Ts[r][col] = v;
    }
    __syncthreads();
    short* xpb = xp + (size_t)b * PROW * CIN;
    const float* ob = ADD ? (Oc + (size_t)b * HW * CIN) : nullptr;
#pragma unroll
    for (int j = 0; j < 2; j++) {
        int slot = j * 256 + t;
        int pix = slot >> 3, ch = (slot & 7) * 8;
        int rp = prow(n0 + pix);
        float v[8];
#pragma unroll
        for (int k = 0; k < 8; k++) v[k] = Ts[ch + k][pix];
        if (ADD) {
            const float* os = ob + (size_t)(n0 + pix) * CIN + c0 + ch;
#pragma unroll
            for (int k = 0; k < 8; k += 4) {
                float4 o4 = *(const float4*)(os + k);
                v[k]   += o4.x * iz; v[k+1] += o4.y * iz;
                v[k+2] += o4.z * iz; v[k+3] += o4.w * iz;
            }
        }
        unsigned pk[4];
#pragma unroll
        for (int k = 0; k < 4; k++)
            pk[k] = f2bf(v[2*k]) | (f2bf(v[2*k+1]) << 16);
        *(uint4*)(xpb + (size_t)rp * CIN + c0 + ch) = *(uint4*)pk;
    }
}

// ---------------------------------------------------------------------------
// 1x1 convs: xt/xc[n][p] = sum_i xp[n][i]*w[p][i] + bias.  M=p(64), N=n(64), K=512
// grid (64 n-tiles, 8: b*2+which)
__global__ __launch_bounds__(256) void k_qk(const short* __restrict__ xp,
        const short* __restrict__ wtop, const short* __restrict__ wcen,
        const float* __restrict__ btop, const float* __restrict__ bcen,
        short* __restrict__ xt, short* __restrict__ xc) {
    __shared__ __align__(16) short As[2048];   // w: 64 rows(p) x 32(i)
    __shared__ __align__(16) short Bs[2048];   // x: 64 rows(n) x 32(i)
    int t = threadIdx.x;
    int n0 = blockIdx.x * 64;
    int b = blockIdx.y >> 1, which = blockIdx.y & 1;
    const short* w    = which ? wcen : wtop;
    const float* bias = which ? bcen : btop;
    short* out        = (which ? xc : xt) + (size_t)b * HW * PABN;
    const short* xb   = xp + (size_t)b * PROW * CIN;

    int arow = t >> 2, ach = t & 3;
    int sch = ach ^ ((arow >> 1) & 3);
    int rp = prow(n0 + arow);
    int lane = t & 63, wid = t >> 6, l15 = lane & 15, q = lane >> 4;
    int wm = wid >> 1, wn = wid & 1;
    int cx = (q ^ ((l15 >> 1) & 3)) * 8;
    ffrag acc[2][2] = {};

    for (int i0 = 0; i0 < CIN; i0 += 32) {
        gload16(w  + (size_t)arow * CIN + i0 + sch * 8, As + t * 8);
        gload16(xb + (size_t)rp   * CIN + i0 + sch * 8, Bs + t * 8);
        __syncthreads();
        bfrag a[2], bb[2];
        a[0]  = *(const bfrag*)(As + (wm * 32 + l15) * 32 + cx);
        a[1]  = *(const bfrag*)(As + (wm * 32 + 16 + l15) * 32 + cx);
        bb[0] = *(const bfrag*)(Bs + (wn * 32 + l15) * 32 + cx);
        bb[1] = *(const bfrag*)(Bs + (wn * 32 + 16 + l15) * 32 + cx);
        acc[0][0] = MFMA(a[0], bb[0], acc[0][0]);
        acc[0][1] = MFMA(a[0], bb[1], acc[0][1]);
        acc[1][0] = MFMA(a[1], bb[0], acc[1][0]);
        acc[1][1] = MFMA(a[1], bb[1], acc[1][1]);
        __syncthreads();
    }
#pragma unroll
    for (int mi = 0; mi < 2; mi++) {
        int p = wm * 32 + mi * 16 + q * 4;
        float4 bv = *(const float4*)(bias + p);
#pragma unroll
        for (int ni = 0; ni < 2; ni++) {
            int nn = n0 + wn * 32 + ni * 16 + l15;
            ffrag v = acc[mi][ni];
            uint2 u;
            u.x = f2bf(v.x + bv.x) | (f2bf(v.y + bv.y) << 16);
            u.y = f2bf(v.z + bv.z) | (f2bf(v.w + bv.w) << 16);
            *(uint2*)(out + (size_t)nn * PABN + p) = u;
        }
    }
}

// ---------------------------------------------------------------------------
// conv3x3 v3: k_fused-v1-style counted-vmcnt pipeline.
//   Per K-step (64): issue stage(ks+1) into buf cur^1 -> vmcnt(8) (waits only
//   for stage(ks), issued a FULL iteration ago) -> B1 -> 32-MFMA cluster on
//   buf cur -> B2.  B2 of step ks-1 protects buf cur^1 reads from this step's
//   overwrite (k_fused v1 proof).  v2's mistakes fixed: zero-slack vmcnt(0)
//   drain -> full-iter slack; flat-loop per-step tap addressing -> nested
//   loops, tap constants computed once per tap.
// LDS 64KB dbuf -> 2 blocks/CU (grid 512 = 2 resident/CU).
// M=n(128), N=o(128). grid (32 n-tiles, 4 o-tiles, B)
template <bool FP32OUT>
__global__ __launch_bounds__(256) void k_conv(const short* __restrict__ xin,
        const short* __restrict__ wT, const float* __restrict__ bias,
        void* __restrict__ outv) {
    __shared__ __align__(16) short As[2][8192];   // pixels: 128 x 64
    __shared__ __align__(16) short Bs[2][8192];   // weights: 128(o) x 64
    int t = threadIdx.x;
    int n0 = blockIdx.x * 128, o0 = blockIdx.y * 128, b = blockIdx.z;
    const short* xb = xin + (size_t)b * PROW * CIN;
    int lane = t & 63, wid = t >> 6, l15 = lane & 15, q = lane >> 4;
    int wm = wid >> 1, wn = wid & 1;
    int arow = t >> 3, ach = t & 7;
    int sch = ach ^ (arow & 7);
    int pr[4];
#pragma unroll
    for (int j = 0; j < 4; j++) pr[j] = prow(n0 + j * 32 + arow);
    ffrag acc[4][4] = {};

    auto stage = [&](int k9s, int i0, int bsel) {
        int kh = k9s / 3, kw = k9s - kh * 3;       // hoisted per-tap by unroll
        int sh = (kh - 1) * 66 + (kw - 1);
        const short* wk = wT + (size_t)k9s * CIN * CIN;
#pragma unroll
        for (int j = 0; j < 4; j++) {
            gload16(xb + (size_t)(pr[j] + sh) * CIN + i0 + sch * 8,
                    &As[bsel][(j * 256 + t) * 8]);
            gload16(wk + (size_t)(o0 + j * 32 + arow) * CIN + i0 + sch * 8,
                    &Bs[bsel][(j * 256 + t) * 8]);
        }
    };

    stage(0, 0, 0);                                // pipeline prologue

    for (int k9 = 0; k9 < 9; ++k9) {
#pragma unroll
        for (int i8 = 0; i8 < 8; ++i8) {
            int ks = k9 * 8 + i8;
            int cur = i8 & 1;                      // == ks & 1
            if (ks < 71) {                         // issue next-step loads
                if (i8 < 7) stage(k9, (i8 + 1) * 64, cur ^ 1);
                else        stage(k9 + 1, 0, cur ^ 1);
                asm volatile("s_waitcnt vmcnt(8)" ::: "memory");  // stage(ks) in
            } else {
                asm volatile("s_waitcnt vmcnt(0)" ::: "memory");
            }
            __builtin_amdgcn_s_barrier();          // B1: tile ks visible to all
            asm volatile("" ::: "memory");
            __builtin_amdgcn_s_setprio(1);
#pragma unroll
            for (int kc = 0; kc < 2; kc++) {
                int cx = (((kc * 4 + q) ^ (l15 & 7))) * 8;
                bfrag a[4], bb[4];
#pragma unroll
                for (int mi = 0; mi < 4; mi++)
                    a[mi] = *(const bfrag*)(&As[cur][(wm * 64 + mi * 16 + l15) * 64 + cx]);
#pragma unroll
                for (int ni = 0; ni < 4; ni++)
                    bb[ni] = *(const bfrag*)(&Bs[cur][(wn * 64 + ni * 16 + l15) * 64 + cx]);
#pragma unroll
                for (int mi = 0; mi < 4; mi++)
#pragma unroll
                    for (int ni = 0; ni < 4; ni++)
                        acc[mi][ni] = MFMA(a[mi], bb[ni], acc[mi][ni]);
            }
            __builtin_amdgcn_s_setprio(0);
            asm volatile("" ::: "memory");
            __builtin_amdgcn_s_barrier();          // B2: reads of buf cur done
            asm volatile("" ::: "memory");
        }
    }
#pragma unroll
    for (int ni = 0; ni < 4; ni++) {
        int o = o0 + wn * 64 + ni * 16 + l15;
        float bv = bias[o];
#pragma unroll
        for (int mi = 0; mi < 4; mi++) {
            int n = n0 + wm * 64 + mi * 16 + q * 4;
            ffrag v = acc[mi][ni];
            if (FP32OUT) {
                float* out = (float*)outv + (size_t)b * CIN * HW;
                *(float4*)(out + (size_t)o * HW + n) =
                    make_float4(v.x + bv, v.y + bv, v.z + bv, v.w + bv);
            } else {
                short* out = (short*)outv + (size_t)b * CIN * HW;
                uint2 u;
                u.x = f2bf(v.x + bv) | (f2bf(v.y + bv) << 16);
                u.y = f2bf(v.z + bv) | (f2bf(v.w + bv) << 16);
                *(uint2*)(out + (size_t)o * HW + n) = u;
            }
        }
    }
}

// ---------------------------------------------------------------------------
// Fused S+PV (v1, measured 120.6us — unchanged):
//   per block: n-tile 128, c-half 256, one batch. Loop m over 4096 step 64:
//     S[128n][64m] = xc.xt^T -> exp -> P in LDS (chunk-swizzled)
//     O[c][n] += xb[c][m-tile] . P^T   (acc VGPR, unscaled; invZ in k_padT)
// 8 waves (512 thr), 1 block/CU, grid 256 XCD-swizzled. LDS 112 KB.
__global__ __launch_bounds__(512) void k_fused(const short* __restrict__ xc,
        const short* __restrict__ xt, const short* __restrict__ xb,
        float* __restrict__ O, float* __restrict__ Zbuf) {
    __shared__ __align__(16) short SM[57344];   // 112 KB
    __shared__ float red[8];
    short* XC  = SM;                 // [128][64]
    short* XT0 = SM + 8192;          // [2][64][64]
    short* XB0 = SM + 16384;         // [2][256][64]
    short* PS  = SM + 49152;         // [128][64]

    int wg = ((blockIdx.x & 7) << 5) | (blockIdx.x >> 3);   // XCD-contiguous
    int b = wg >> 6, chalf = (wg >> 5) & 1, ntile = wg & 31;
    int n0 = ntile * 128, c0 = chalf * 256;
    const short* xcb = xc + (size_t)b * HW * PABN;
    const short* xtb = xt + (size_t)b * HW * PABN;
    const short* xbb = xb + (size_t)b * CIN * HW;

    int t = threadIdx.x;
    int lane = t & 63, wid = t >> 6, l15 = lane & 15, q = lane >> 4;
    int srow = t >> 3, sch = (t & 7) ^ (srow & 7);   // staging row / swizzled chunk
    int wc = wid >> 1, wnn = wid & 1;                // PV wave roles: c-quarter, n-half

    // prologue: persistent xc tile + step-0 xt/xb
    {
        const short* s0 = xcb + (size_t)(n0 + srow) * PABN + sch * 8;
        gload16(s0, XC + t * 8);
        gload16(s0 + 64 * PABN, XC + 4096 + t * 8);
        gload16(xtb + (size_t)srow * PABN + sch * 8, XT0 + t * 8);
#pragma unroll
        for (int p = 0; p < 4; p++)
            gload16(xbb + (size_t)(c0 + p * 64 + srow) * HW + sch * 8,
                    XB0 + (p * 512 + t) * 8);
    }
    asm volatile("s_waitcnt vmcnt(0)" ::: "memory");
    __builtin_amdgcn_s_barrier();
    asm volatile("" ::: "memory");

    // xc A-fragments are loop-invariant: hoist (wave wid owns S rows [wid*16,+16))
    bfrag aS[2];
#pragma unroll
    for (int kc = 0; kc < 2; kc++)
        aS[kc] = *(const bfrag*)(XC + (wid * 16 + l15) * 64
                                 + ((kc * 4 + q) ^ (l15 & 7)) * 8);

    ffrag acc[4][4] = {};
    float zacc = 0.f;

    for (int it = 0; it < 64; ++it) {
        int cur = it & 1;
        const short* XTc = XT0 + cur * 4096;
        const short* XBc = XB0 + cur * 16384;
        if (it < 63) {                       // issue next-step staging, keep in flight
            int m1 = (it + 1) * 64, nxt = cur ^ 1;
            gload16(xtb + (size_t)(m1 + srow) * PABN + sch * 8,
                    XT0 + nxt * 4096 + t * 8);
#pragma unroll
            for (int p = 0; p < 4; p++)
                gload16(xbb + (size_t)(c0 + p * 64 + srow) * HW + m1 + sch * 8,
                        XB0 + nxt * 16384 + (p * 512 + t) * 8);
            asm volatile("s_waitcnt vmcnt(5)" ::: "memory");   // wait prev group only
        } else {
            asm volatile("s_waitcnt vmcnt(0)" ::: "memory");
        }
        __builtin_amdgcn_s_barrier();
        asm volatile("" ::: "memory");

        // ---- S phase: wave wid computes S rows [wid*16,+16) x m[0,64)
        ffrag s[4] = {};
        __builtin_amdgcn_s_setprio(1);
#pragma unroll
        for (int ni = 0; ni < 4; ni++)
#pragma unroll
            for (int kc = 0; kc < 2; kc++) {
                bfrag bf = *(const bfrag*)(XTc + (ni * 16 + l15) * 64
                                           + ((kc * 4 + q) ^ (l15 & 7)) * 8);
                s[ni] = MFMA(aS[kc], bf, s[ni]);
            }
        __builtin_amdgcn_s_setprio(0);
        // exp + write P (bf16) chunk-swizzled: logical chunk cc at pos cc^(row&7)
        int nrow = wid * 16 + q * 4;
#pragma unroll
        for (int ni = 0; ni < 4; ni++) {
            int cc = ni * 2 + (l15 >> 3), j = l15 & 7;
#pragma unroll
            for (int r = 0; r < 4; r++) {
                float e = __expf(s[ni][r]);
                zacc += e;
                PS[(nrow + r) * 64 + (cc ^ ((nrow + r) & 7)) * 8 + j] =
                    (short)f2bf(e);
            }
        }
        asm volatile("s_waitcnt lgkmcnt(0)" ::: "memory");
        __builtin_amdgcn_s_barrier();
        asm volatile("" ::: "memory");

        // ---- PV phase: acc[c][n] += xb . P^T  (wave: c 64 x n 64)
        __builtin_amdgcn_s_setprio(1);
#pragma unroll
        for (int kc = 0; kc < 2; kc++) {
            int cx = ((kc * 4 + q) ^ (l15 & 7)) * 8;
            bfrag av[4], bv[4];
#pragma unroll
            for (int ci = 0; ci < 4; ci++)
                av[ci] = *(const bfrag*)(XBc + (wc * 64 + ci * 16 + l15) * 64 + cx);
#pragma unroll
            for (int nj = 0; nj < 4; nj++)
                bv[nj] = *(const bfrag*)(PS + (wnn * 64 + nj * 16 + l15) * 64 + cx);
#pragma unroll
            for (int ci = 0; ci < 4; ci++)
#pragma unroll
                for (int nj = 0; nj < 4; nj++)
                    acc[ci][nj] = MFMA(av[ci], bv[nj], acc[ci][nj]);
        }
        __builtin_amdgcn_s_setprio(0);
        asm volatile("" ::: "memory");
        __builtin_amdgcn_s_barrier();
        asm volatile("" ::: "memory");
    }

    // ---- z reduce (chalf 0 only contributes; both halves computed same S)
#pragma unroll
    for (int off = 32; off > 0; off >>= 1) zacc += __shfl_down(zacc, off, 64);
    if (lane == 0) red[wid] = zacc;
    __syncthreads();
    if (chalf == 0 && t == 0) {
        float z = 0.f;
#pragma unroll
        for (int i = 0; i < 8; i++) z += red[i];
        Zbuf[b * 32 + ntile] = z;
    }
    // ---- O store (unscaled fp32, [n][c])
    float* Ob = O + (size_t)b * HW * CIN;
#pragma unroll
    for (int ci = 0; ci < 4; ci++)
#pragma unroll
        for (int nj = 0; nj < 4; nj++) {
            int n = n0 + wnn * 64 + nj * 16 + l15;
            int c = c0 + wc * 64 + ci * 16 + q * 4;
            ffrag v = acc[ci][nj];
            *(float4*)(Ob + (size_t)n * CIN + c) =
                make_float4(v.x, v.y, v.z, v.w);
        }
}

// ---------------------------------------------------------------------------
// Reduce Zbuf[b][0..31] -> Z[b]. 1 block, 256 thr (wave per batch).
__global__ __launch_bounds__(256) void k_redz(const float* __restrict__ Zbuf,
        float* __restrict__ Z) {
    int wid = threadIdx.x >> 6, lane = threadIdx.x & 63;
    float s = (lane < 32) ? Zbuf[wid * 32 + lane] : 0.f;
#pragma unroll
    for (int off = 32; off > 0; off >>= 1) s += __shfl_down(s, off, 64);
    if (lane == 0) Z[wid] = s;
}

// ---------------------------------------------------------------------------
extern "C" void kernel_launch(void* const* d_in, const int* in_sizes, int n_in,
                              void* d_out, int out_size, void* d_ws, size_t ws_size,
                              hipStream_t stream) {
    const float* x     = (const float*)d_in[0];
    const float* w_top = (const float*)d_in[1];
    const float* b_top = (const float*)d_in[2];
    const float* w_cen = (const float*)d_in[3];
    const float* b_cen = (const float*)d_in[4];
    const float* w_bot = (const float*)d_in[5];
    const float* b_bot = (const float*)d_in[6];
    const float* w_out = (const float*)d_in[7];
    const float* b_out = (const float*)d_in[8];

    char* W = (char*)d_ws;
    short* xp   = (short*)(W);               // 17,842,176 B (also reused as yp)
    short* xt   = (short*)(W + 17842176);    //  2,097,152
    short* xc   = (short*)(W + 19939328);    //  2,097,152
    short* wtb  = (short*)(W + 22036480);    //     65,536
    short* wcb  = (short*)(W + 22102016);    //     65,536
    short* wbT  = (short*)(W + 22167552);    //  4,718,592
    short* woT  = (short*)(W + 26886144);    //  4,718,592
    short* xbc  = (short*)(W + 31604736);    // 16,777,216
    float* O    = (float*)(W + 48381952);    // 33,554,432 (unscaled PV output)
    float* Z    = (float*)(W + 81936384);    //        512
    float* Zbuf = (float*)(W + 81936896);    //     16,384 (uses 128 floats)

    k_fill0<<<4356, 256, 0, stream>>>((uint4*)xp);           // zero padded buffer
    k_wpc<<<dim3(32, 2), 256, 0, stream>>>(w_top, w_cen, wtb, wcb);
    k_w9<<<dim3(512, 2, 2), 256, 0, stream>>>(w_bot, w_out, wbT, woT);
    k_padT<false><<<dim3(64, 8, BATCH), 256, 0, stream>>>(x, nullptr, nullptr, xp);
    k_qk<<<dim3(64, 8), 256, 0, stream>>>(xp, wtb, wcb, b_top, b_cen, xt, xc);
    k_conv<false><<<dim3(32, 4, BATCH), 256, 0, stream>>>(xp, wbT, b_bot, xbc);
    k_fused<<<dim3(256), 512, 0, stream>>>(xc, xt, xbc, O, Zbuf);
    k_redz<<<1, 256, 0, stream>>>(Zbuf, Z);
    k_padT<true><<<dim3(64, 8, BATCH), 256, 0, stream>>>(x, O, Z, xp);  // y -> xp
    k_conv<true><<<dim3(32, 4, BATCH), 256, 0, stream>>>(xp, woT, b_out, (float*)d_out);
}

// Round 9
// 388.984 us; speedup vs baseline: 1.2383x; 1.0009x over previous
//
#include <hip/hip_runtime.h>
#include <math.h>

#define BATCH 4
#define CIN   512
#define PABN  64
#define HW    4096
#define PROW  4356            // 66*66 padded pixel rows

typedef __attribute__((ext_vector_type(8))) short bfrag;   // 8 bf16
typedef __attribute__((ext_vector_type(4))) float ffrag;   // 4 fp32
#define MFMA(a, b, c) __builtin_amdgcn_mfma_f32_16x16x32_bf16(a, b, c, 0, 0, 0)

__device__ __forceinline__ void gload16(const void* g, void* l) {
    __builtin_amdgcn_global_load_lds(
        (const __attribute__((address_space(1))) unsigned int*)g,
        (__attribute__((address_space(3))) unsigned int*)l, 16, 0, 0);
}

__device__ __forceinline__ unsigned f2bf(float f) {   // fp32 -> bf16 bits, RNE
    unsigned u = __float_as_uint(f);
    return (u + 0x7fffu + ((u >> 16) & 1u)) >> 16;
}

// padded row index for pixel n: (h+1)*66 + (w+1) = n + 2*(n>>6) + 67
__device__ __forceinline__ int prow(int n) { return n + 2 * (n >> 6) + 67; }

// ---------------------------------------------------------------------------
__global__ __launch_bounds__(256) void k_fill0(uint4* __restrict__ p) {
    uint4 z; z.x = z.y = z.z = z.w = 0u;
    p[(size_t)blockIdx.x * 256 + threadIdx.x] = z;
}

// w_top/w_cen [64][512] fp32 -> bf16 (layout kept: [p][i], K=i contiguous)
__global__ __launch_bounds__(256) void k_wpc(const float* __restrict__ wt,
        const float* __restrict__ wc, short* __restrict__ ot, short* __restrict__ oc) {
    const float* src = blockIdx.y ? wc : wt;
    short* dst       = blockIdx.y ? oc : ot;
    int idx = (blockIdx.x * 256 + threadIdx.x) * 4;
    float4 v = *(const float4*)(src + idx);
    uint2 u;
    u.x = f2bf(v.x) | (f2bf(v.y) << 16);
    u.y = f2bf(v.z) | (f2bf(v.w) << 16);
    *(uint2*)(dst + idx) = u;
}

// w [O][I][3][3] fp32 -> wT[k][o][i] bf16
__global__ __launch_bounds__(256) void k_w9(const float* __restrict__ wb,
        const float* __restrict__ wo, short* __restrict__ wbT, short* __restrict__ woT) {
    const float* w = blockIdx.z ? wo : wb;
    short* wT      = blockIdx.z ? woT : wbT;
    int o = blockIdx.x;
    int i = blockIdx.y * 256 + threadIdx.x;
    const float* src = w + ((size_t)o * CIN + i) * 9;
    float v[9];
#pragma unroll
    for (int k = 0; k < 9; k++) v[k] = src[k];
#pragma unroll
    for (int k = 0; k < 9; k++)
        wT[((size_t)k * CIN + o) * CIN + i] = (short)f2bf(v[k]);
}

// ---------------------------------------------------------------------------
// x [B][512][4096] fp32 (ADD: + invZ * O [n][c] fp32, raw-reshape-equivalent) ->
// pixel-major padded bf16 xp [B][4356][512]. Borders pre-zeroed by k_fill0.
// grid (64 pix-tiles, 8 ch-tiles, B)
template <bool ADD>
__global__ __launch_bounds__(256) void k_padT(const float* __restrict__ x,
        const float* __restrict__ Oc, const float* __restrict__ Zp,
        short* __restrict__ xp) {
    __shared__ float Ts[64][68];
    int t = threadIdx.x;
    int n0 = blockIdx.x * 64, c0 = blockIdx.y * 64, b = blockIdx.z;
    float iz = ADD ? (1.0f / Zp[b]) : 1.0f;
    const float* xb = x + ((size_t)b * CIN + c0) * HW;
#pragma unroll
    for (int j = 0; j < 4; j++) {
        int slot = j * 256 + t;
        int r = slot >> 4, col = (slot & 15) * 4;
        float4 v = *(const float4*)(xb + (size_t)r * HW + n0 + col);
        *(float4*)&Ts[r][col] = v;
    }
    __syncthreads();
    short* xpb = xp + (size_t)b * PROW * CIN;
    const float* ob = ADD ? (Oc + (size_t)b * HW * CIN) : nullptr;
#pragma unroll
    for (int j = 0; j < 2; j++) {
        int slot = j * 256 + t;
        int pix = slot >> 3, ch = (slot & 7) * 8;
        int rp = prow(n0 + pix);
        float v[8];
#pragma unroll
        for (int k = 0; k < 8; k++) v[k] = Ts[ch + k][pix];
        if (ADD) {
            const float* os = ob + (size_t)(n0 + pix) * CIN + c0 + ch;
#pragma unroll
            for (int k = 0; k < 8; k += 4) {
                float4 o4 = *(const float4*)(os + k);
                v[k]   += o4.x * iz; v[k+1] += o4.y * iz;
                v[k+2] += o4.z * iz; v[k+3] += o4.w * iz;
            }
        }
        unsigned pk[4];
#pragma unroll
        for (int k = 0; k < 4; k++)
            pk[k] = f2bf(v[2*k]) | (f2bf(v[2*k+1]) << 16);
        *(uint4*)(xpb + (size_t)rp * CIN + c0 + ch) = *(uint4*)pk;
    }
}

// ---------------------------------------------------------------------------
// 1x1 convs: xt/xc[n][p] = sum_i xp[n][i]*w[p][i] + bias.  M=p(64), N=n(64), K=512
// grid (64 n-tiles, 8: b*2+which)
__global__ __launch_bounds__(256) void k_qk(const short* __restrict__ xp,
        const short* __restrict__ wtop, const short* __restrict__ wcen,
        const float* __restrict__ btop, const float* __restrict__ bcen,
        short* __restrict__ xt, short* __restrict__ xc) {
    __shared__ __align__(16) short As[2048];   // w: 64 rows(p) x 32(i)
    __shared__ __align__(16) short Bs[2048];   // x: 64 rows(n) x 32(i)
    int t = threadIdx.x;
    int n0 = blockIdx.x * 64;
    int b = blockIdx.y >> 1, which = blockIdx.y & 1;
    const short* w    = which ? wcen : wtop;
    const float* bias = which ? bcen : btop;
    short* out        = (which ? xc : xt) + (size_t)b * HW * PABN;
    const short* xb   = xp + (size_t)b * PROW * CIN;

    int arow = t >> 2, ach = t & 3;
    int sch = ach ^ ((arow >> 1) & 3);
    int rp = prow(n0 + arow);
    int lane = t & 63, wid = t >> 6, l15 = lane & 15, q = lane >> 4;
    int wm = wid >> 1, wn = wid & 1;
    int cx = (q ^ ((l15 >> 1) & 3)) * 8;
    ffrag acc[2][2] = {};

    for (int i0 = 0; i0 < CIN; i0 += 32) {
        gload16(w  + (size_t)arow * CIN + i0 + sch * 8, As + t * 8);
        gload16(xb + (size_t)rp   * CIN + i0 + sch * 8, Bs + t * 8);
        __syncthreads();
        bfrag a[2], bb[2];
        a[0]  = *(const bfrag*)(As + (wm * 32 + l15) * 32 + cx);
        a[1]  = *(const bfrag*)(As + (wm * 32 + 16 + l15) * 32 + cx);
        bb[0] = *(const bfrag*)(Bs + (wn * 32 + l15) * 32 + cx);
        bb[1] = *(const bfrag*)(Bs + (wn * 32 + 16 + l15) * 32 + cx);
        acc[0][0] = MFMA(a[0], bb[0], acc[0][0]);
        acc[0][1] = MFMA(a[0], bb[1], acc[0][1]);
        acc[1][0] = MFMA(a[1], bb[0], acc[1][0]);
        acc[1][1] = MFMA(a[1], bb[1], acc[1][1]);
        __syncthreads();
    }
#pragma unroll
    for (int mi = 0; mi < 2; mi++) {
        int p = wm * 32 + mi * 16 + q * 4;
        float4 bv = *(const float4*)(bias + p);
#pragma unroll
        for (int ni = 0; ni < 2; ni++) {
            int nn = n0 + wn * 32 + ni * 16 + l15;
            ffrag v = acc[mi][ni];
            uint2 u;
            u.x = f2bf(v.x + bv.x) | (f2bf(v.y + bv.y) << 16);
            u.y = f2bf(v.z + bv.z) | (f2bf(v.w + bv.w) << 16);
            *(uint2*)(out + (size_t)nn * PABN + p) = u;
        }
    }
}

// ---------------------------------------------------------------------------
// conv3x3 v3 (kept — round-8 win): counted-vmcnt pipeline, vmcnt(8) with
// full-iteration slack, per-tap hoisted addressing. LDS 64KB dbuf.
// M=n(128), N=o(128). grid (32 n-tiles, 4 o-tiles, B)
template <bool FP32OUT>
__global__ __launch_bounds__(256) void k_conv(const short* __restrict__ xin,
        const short* __restrict__ wT, const float* __restrict__ bias,
        void* __restrict__ outv) {
    __shared__ __align__(16) short As[2][8192];   // pixels: 128 x 64
    __shared__ __align__(16) short Bs[2][8192];   // weights: 128(o) x 64
    int t = threadIdx.x;
    int n0 = blockIdx.x * 128, o0 = blockIdx.y * 128, b = blockIdx.z;
    const short* xb = xin + (size_t)b * PROW * CIN;
    int lane = t & 63, wid = t >> 6, l15 = lane & 15, q = lane >> 4;
    int wm = wid >> 1, wn = wid & 1;
    int arow = t >> 3, ach = t & 7;
    int sch = ach ^ (arow & 7);
    int pr[4];
#pragma unroll
    for (int j = 0; j < 4; j++) pr[j] = prow(n0 + j * 32 + arow);
    ffrag acc[4][4] = {};

    auto stage = [&](int k9s, int i0, int bsel) {
        int kh = k9s / 3, kw = k9s - kh * 3;       // hoisted per-tap by unroll
        int sh = (kh - 1) * 66 + (kw - 1);
        const short* wk = wT + (size_t)k9s * CIN * CIN;
#pragma unroll
        for (int j = 0; j < 4; j++) {
            gload16(xb + (size_t)(pr[j] + sh) * CIN + i0 + sch * 8,
                    &As[bsel][(j * 256 + t) * 8]);
            gload16(wk + (size_t)(o0 + j * 32 + arow) * CIN + i0 + sch * 8,
                    &Bs[bsel][(j * 256 + t) * 8]);
        }
    };

    stage(0, 0, 0);                                // pipeline prologue

    for (int k9 = 0; k9 < 9; ++k9) {
#pragma unroll
        for (int i8 = 0; i8 < 8; ++i8) {
            int ks = k9 * 8 + i8;
            int cur = i8 & 1;                      // == ks & 1
            if (ks < 71) {                         // issue next-step loads
                if (i8 < 7) stage(k9, (i8 + 1) * 64, cur ^ 1);
                else        stage(k9 + 1, 0, cur ^ 1);
                asm volatile("s_waitcnt vmcnt(8)" ::: "memory");  // stage(ks) in
            } else {
                asm volatile("s_waitcnt vmcnt(0)" ::: "memory");
            }
            __builtin_amdgcn_s_barrier();          // B1: tile ks visible to all
            asm volatile("" ::: "memory");
            __builtin_amdgcn_s_setprio(1);
#pragma unroll
            for (int kc = 0; kc < 2; kc++) {
                int cx = (((kc * 4 + q) ^ (l15 & 7))) * 8;
                bfrag a[4], bb[4];
#pragma unroll
                for (int mi = 0; mi < 4; mi++)
                    a[mi] = *(const bfrag*)(&As[cur][(wm * 64 + mi * 16 + l15) * 64 + cx]);
#pragma unroll
                for (int ni = 0; ni < 4; ni++)
                    bb[ni] = *(const bfrag*)(&Bs[cur][(wn * 64 + ni * 16 + l15) * 64 + cx]);
#pragma unroll
                for (int mi = 0; mi < 4; mi++)
#pragma unroll
                    for (int ni = 0; ni < 4; ni++)
                        acc[mi][ni] = MFMA(a[mi], bb[ni], acc[mi][ni]);
            }
            __builtin_amdgcn_s_setprio(0);
            asm volatile("" ::: "memory");
            __builtin_amdgcn_s_barrier();          // B2: reads of buf cur done
            asm volatile("" ::: "memory");
        }
    }
#pragma unroll
    for (int ni = 0; ni < 4; ni++) {
        int o = o0 + wn * 64 + ni * 16 + l15;
        float bv = bias[o];
#pragma unroll
        for (int mi = 0; mi < 4; mi++) {
            int n = n0 + wm * 64 + mi * 16 + q * 4;
            ffrag v = acc[mi][ni];
            if (FP32OUT) {
                float* out = (float*)outv + (size_t)b * CIN * HW;
                *(float4*)(out + (size_t)o * HW + n) =
                    make_float4(v.x + bv, v.y + bv, v.z + bv, v.w + bv);
            } else {
                short* out = (short*)outv + (size_t)b * CIN * HW;
                uint2 u;
                u.x = f2bf(v.x + bv) | (f2bf(v.y + bv) << 16);
                u.y = f2bf(v.z + bv) | (f2bf(v.w + bv) << 16);
                *(uint2*)(out + (size_t)o * HW + n) = u;
            }
        }
    }
}

// ---------------------------------------------------------------------------
// Fused S+PV v5: c-FULL blocks — no duplicate S work.
//   Tile 64n x 512c, one batch. 8 waves (512 thr), 1 block/CU, grid 256
//   XCD-swizzled. Wave roles: S phase wave=(nset=wid&3, mhalf=wid>>2) computes
//   16n x 32m (4 MFMA); exp 8 vals/thread (HALF of v1, computed once, not per
//   c-half). PV: wave owns c-64 x n-64 (32 MFMA).
//   LDS 90KB: XT[2][64][64] dbuf | XB[512][64] SINGLE | PS[64][64] (XC staged
//   through PS in prologue). Per iter, 2 barriers:
//     A: issue XT(it+1); S 4-MFMA; exp->PS
//     B1: lgkmcnt(0) + vmcnt(1)  [XB(it) landed; XT(it+1) may fly]
//     PV 32 MFMA (XB + PS)
//     B2: vmcnt(0)               [XT(it+1) landed; XB reads done]
//     C: issue XB(it+1) x8       [lands under next A-phase, checked at next B1]
__global__ __launch_bounds__(512) void k_fused(const short* __restrict__ xc,
        const short* __restrict__ xt, const short* __restrict__ xb,
        float* __restrict__ O, float* __restrict__ Zbuf) {
    __shared__ __align__(16) short SM[45056];   // 90112 B
    __shared__ float red[8];
    short* XT0 = SM;                  // [2][64][64]
    short* XBs = SM + 8192;           // [512][64] single
    short* PS  = SM + 40960;          // [64][64]

    int wg = ((blockIdx.x & 7) << 5) | (blockIdx.x >> 3);   // XCD-contiguous
    int b = wg >> 6, ntile = wg & 63;
    int n0 = ntile * 64;
    const short* xcb = xc + (size_t)b * HW * PABN;
    const short* xtb = xt + (size_t)b * HW * PABN;
    const short* xbb = xb + (size_t)b * CIN * HW;

    int t = threadIdx.x;
    int lane = t & 63, wid = t >> 6, l15 = lane & 15, q = lane >> 4;
    int srow = t >> 3, sch = (t & 7) ^ (srow & 7);   // staging row / swizzled chunk
    int nset = wid & 3, mhalf = wid >> 2;            // S-phase wave role

    // ---- prologue: XC -> PS area, XT(0), XB(0)
    gload16(xcb + (size_t)(n0 + srow) * PABN + sch * 8, PS + t * 8);
    gload16(xtb + (size_t)srow * PABN + sch * 8, XT0 + t * 8);
#pragma unroll
    for (int j = 0; j < 8; j++)
        gload16(xbb + (size_t)(j * 64 + srow) * HW + sch * 8,
                XBs + (j * 512 + t) * 8);
    asm volatile("s_waitcnt vmcnt(0)" ::: "memory");
    __builtin_amdgcn_s_barrier();
    asm volatile("" ::: "memory");
    bfrag aS[2];                                // loop-invariant xc A-frags
#pragma unroll
    for (int kc = 0; kc < 2; kc++)
        aS[kc] = *(const bfrag*)(PS + (nset * 16 + l15) * 64
                                 + ((kc * 4 + q) ^ (l15 & 7)) * 8);
    asm volatile("s_waitcnt lgkmcnt(0)" ::: "memory");
    __builtin_amdgcn_s_barrier();               // PS now reusable
    asm volatile("" ::: "memory");

    ffrag acc[4][4] = {};
    float zacc = 0.f;
    int nrow = nset * 16 + q * 4;

    for (int it = 0; it < 64; ++it) {
        const short* XTc = XT0 + (it & 1) * 4096;
        // ---- A: issue XT(it+1); S(it) 4 MFMA; exp -> PS
        if (it < 63)
            gload16(xtb + (size_t)((it + 1) * 64 + srow) * PABN + sch * 8,
                    XT0 + ((it & 1) ^ 1) * 4096 + t * 8);
        ffrag s[2] = {};
        __builtin_amdgcn_s_setprio(1);
#pragma unroll
        for (int mi = 0; mi < 2; mi++)
#pragma unroll
            for (int kc = 0; kc < 2; kc++) {
                bfrag bf = *(const bfrag*)(XTc + (mhalf * 32 + mi * 16 + l15) * 64
                                           + ((kc * 4 + q) ^ (l15 & 7)) * 8);
                s[mi] = MFMA(aS[kc], bf, s[mi]);
            }
        __builtin_amdgcn_s_setprio(0);
#pragma unroll
        for (int mi = 0; mi < 2; mi++) {
            int cc = mhalf * 4 + mi * 2 + (l15 >> 3), jj = l15 & 7;
#pragma unroll
            for (int r = 0; r < 4; r++) {
                float e = __expf(s[mi][r]);
                zacc += e;
                PS[(nrow + r) * 64 + (cc ^ ((nrow + r) & 7)) * 8 + jj] =
                    (short)f2bf(e);
            }
        }
        if (it < 63) asm volatile("s_waitcnt vmcnt(1) lgkmcnt(0)" ::: "memory");
        else         asm volatile("s_waitcnt vmcnt(0) lgkmcnt(0)" ::: "memory");
        __builtin_amdgcn_s_barrier();           // B1: PS(it)+XB(it) visible
        asm volatile("" ::: "memory");
        // ---- PV: acc[c][n] += xb . P^T  (wave: c-64 x n-64)
        __builtin_amdgcn_s_setprio(1);
#pragma unroll
        for (int kc = 0; kc < 2; kc++) {
            int cx = ((kc * 4 + q) ^ (l15 & 7)) * 8;
            bfrag av[4], bv[4];
#pragma unroll
            for (int ci = 0; ci < 4; ci++)
                av[ci] = *(const bfrag*)(XBs + (wid * 64 + ci * 16 + l15) * 64 + cx);
#pragma unroll
            for (int nj = 0; nj < 4; nj++)
                bv[nj] = *(const bfrag*)(PS + (nj * 16 + l15) * 64 + cx);
#pragma unroll
            for (int ci = 0; ci < 4; ci++)
#pragma unroll
                for (int nj = 0; nj < 4; nj++)
                    acc[ci][nj] = MFMA(av[ci], bv[nj], acc[ci][nj]);
        }
        __builtin_amdgcn_s_setprio(0);
        if (it < 63) asm volatile("s_waitcnt vmcnt(0)" ::: "memory"); // XT(it+1) in
        __builtin_amdgcn_s_barrier();           // B2: XB/PS reads done
        asm volatile("" ::: "memory");
        // ---- C: issue XB(it+1) staging (lands under next A phase)
        if (it < 63) {
            int m1 = (it + 1) * 64;
#pragma unroll
            for (int j = 0; j < 8; j++)
                gload16(xbb + (size_t)(j * 64 + srow) * HW + m1 + sch * 8,
                        XBs + (j * 512 + t) * 8);
        }
    }

    // ---- z reduce (every value exp'd exactly once)
#pragma unroll
    for (int off = 32; off > 0; off >>= 1) zacc += __shfl_down(zacc, off, 64);
    if (lane == 0) red[wid] = zacc;
    __syncthreads();
    if (t == 0) {
        float z = 0.f;
#pragma unroll
        for (int i = 0; i < 8; i++) z += red[i];
        Zbuf[b * 64 + ntile] = z;
    }
    // ---- O store (unscaled fp32, [n][c]; invZ applied in k_padT<true>)
    float* Ob = O + (size_t)b * HW * CIN;
#pragma unroll
    for (int ci = 0; ci < 4; ci++)
#pragma unroll
        for (int nj = 0; nj < 4; nj++) {
            int n = n0 + nj * 16 + l15;
            int c = wid * 64 + ci * 16 + q * 4;
            ffrag v = acc[ci][nj];
            *(float4*)(Ob + (size_t)n * CIN + c) =
                make_float4(v.x, v.y, v.z, v.w);
        }
}

// ---------------------------------------------------------------------------
// Reduce Zbuf[b][0..63] -> Z[b]. 1 block, 256 thr (wave per batch).
__global__ __launch_bounds__(256) void k_redz(const float* __restrict__ Zbuf,
        float* __restrict__ Z) {
    int wid = threadIdx.x >> 6, lane = threadIdx.x & 63;
    float s = Zbuf[wid * 64 + lane];
#pragma unroll
    for (int off = 32; off > 0; off >>= 1) s += __shfl_down(s, off, 64);
    if (lane == 0) Z[wid] = s;
}

// ---------------------------------------------------------------------------
extern "C" void kernel_launch(void* const* d_in, const int* in_sizes, int n_in,
                              void* d_out, int out_size, void* d_ws, size_t ws_size,
                              hipStream_t stream) {
    const float* x     = (const float*)d_in[0];
    const float* w_top = (const float*)d_in[1];
    const float* b_top = (const float*)d_in[2];
    const float* w_cen = (const float*)d_in[3];
    const float* b_cen = (const float*)d_in[4];
    const float* w_bot = (const float*)d_in[5];
    const float* b_bot = (const float*)d_in[6];
    const float* w_out = (const float*)d_in[7];
    const float* b_out = (const float*)d_in[8];

    char* W = (char*)d_ws;
    short* xp   = (short*)(W);               // 17,842,176 B (also reused as yp)
    short* xt   = (short*)(W + 17842176);    //  2,097,152
    short* xc   = (short*)(W + 19939328);    //  2,097,152
    short* wtb  = (short*)(W + 22036480);    //     65,536
    short* wcb  = (short*)(W + 22102016);    //     65,536
    short* wbT  = (short*)(W + 22167552);    //  4,718,592
    short* woT  = (short*)(W + 26886144);    //  4,718,592
    short* xbc  = (short*)(W + 31604736);    // 16,777,216
    float* O    = (float*)(W + 48381952);    // 33,554,432 (unscaled PV output)
    float* Z    = (float*)(W + 81936384);    //        512
    float* Zbuf = (float*)(W + 81936896);    //     16,384 (uses 256 floats)

    k_fill0<<<4356, 256, 0, stream>>>((uint4*)xp);           // zero padded buffer
    k_wpc<<<dim3(32, 2), 256, 0, stream>>>(w_top, w_cen, wtb, wcb);
    k_w9<<<dim3(512, 2, 2), 256, 0, stream>>>(w_bot, w_out, wbT, woT);
    k_padT<false><<<dim3(64, 8, BATCH), 256, 0, stream>>>(x, nullptr, nullptr, xp);
    k_qk<<<dim3(64, 8), 256, 0, stream>>>(xp, wtb, wcb, b_top, b_cen, xt, xc);
    k_conv<false><<<dim3(32, 4, BATCH), 256, 0, stream>>>(xp, wbT, b_bot, xbc);
    k_fused<<<dim3(256), 512, 0, stream>>>(xc, xt, xbc, O, Zbuf);
    k_redz<<<1, 256, 0, stream>>>(Zbuf, Z);
    k_padT<true><<<dim3(64, 8, BATCH), 256, 0, stream>>>(x, O, Z, xp);  // y -> xp
    k_conv<true><<<dim3(32, 4, BATCH), 256, 0, stream>>>(xp, woT, b_out, (float*)d_out);
}